// Round 3
// baseline (546.043 us; speedup 1.0000x reference)
//
#include <hip/hip_runtime.h>
#include <math.h>

#define LL 4096
#define DD 2048

typedef __attribute__((ext_vector_type(8))) short short8;   // 8 x bf16
typedef __attribute__((ext_vector_type(4))) float f32x4;
typedef unsigned int u32;
typedef unsigned short u16;

__device__ __constant__ float POS_W_c[8] = {0.95f, 0.9f, 0.85f, 0.5f, 0.4f, 0.2f, 0.15f, 0.05f};

// ---------- helpers ----------
static __device__ inline u32 f2bf(float f) {
    u32 u = __builtin_bit_cast(u32, f);
    return (u + 0x7fffu + ((u >> 16) & 1u)) >> 16;
}
static __device__ inline u32 cvt2_bf16(float a, float b) {
    return f2bf(a) | (f2bf(b) << 16);
}
static __device__ inline short8 pack8_bf16(float4 a, float4 b) {
    uint4 u = make_uint4(cvt2_bf16(a.x, a.y), cvt2_bf16(a.z, a.w),
                         cvt2_bf16(b.x, b.y), cvt2_bf16(b.z, b.w));
    return __builtin_bit_cast(short8, u);
}

// ---------- kernel 1: per-token stats ----------
__global__ __launch_bounds__(256) void row_stats_k(
    const float* __restrict__ tv, const int* __restrict__ pos_idx,
    const float* __restrict__ conf, const float* __restrict__ res,
    const float* __restrict__ k_spring,
    float* __restrict__ m_arr, float* __restrict__ bh_arr,
    float* __restrict__ spring_arr, int* __restrict__ coll_arr)
{
    int i = blockIdx.x;
    int t = threadIdx.x;
    const float4* row = (const float4*)(tv + (size_t)i * DD);
    float s = 0.0f;
#pragma unroll
    for (int c = 0; c < 2; ++c) {
        float4 v = row[t + c * 256];
        s += v.x * v.x + v.y * v.y + v.z * v.z + v.w * v.w;
    }
#pragma unroll
    for (int o = 32; o; o >>= 1) s += __shfl_xor(s, o);
    __shared__ float tmp[4];
    if ((t & 63) == 0) tmp[t >> 6] = s;
    __syncthreads();
    if (t == 0) {
        float tot = tmp[0] + tmp[1] + tmp[2] + tmp[3];
        float norm = sqrtf(tot);
        int p = pos_idx[i] & 7;
        float m = norm * POS_W_c[p] * (1.0f + res[i]);
        float cf = conf[i];
        bool col = (cf <= 0.1f);
        float gap = col ? 1.0f : (cf - 0.1f);
        float bh = col ? -1e6f : (-0.01f / (gap * gap));
        m_arr[i] = m;
        bh_arr[i] = bh;
        // reference: row_skip = (bh < -1e5) — includes NEAR-collapsed rows
        // (conf slightly above 0.1, gap < 3.162e-4), not just conf<=0.1.
        coll_arr[i] = (bh < -1e5f) ? 1 : 0;
        spring_arr[i] = 1.0f / (1.0f + __expf(-k_spring[p]));
    }
}

// ---------- kernel 2: scores + row softmax ----------
__global__ __launch_bounds__(256) void scores_k(
    const int* __restrict__ pos_idx, const int* __restrict__ depth,
    const int* __restrict__ token_pos, const int* __restrict__ slot_idx,
    const float* __restrict__ m_arr, const float* __restrict__ bh_arr,
    const float* __restrict__ spring_arr, const int* __restrict__ coll_arr,
    const float* __restrict__ G_micro, const float* __restrict__ G_macro,
    const float* __restrict__ temperature,
    float* __restrict__ scores, float* __restrict__ Amat)
{
    int i = blockIdx.x;
    int t = threadIdx.x;
    int lane = t & 63, wid = t >> 6;

    __shared__ float sigG[64];
    __shared__ float red[4];
    if (t < 64) sigG[t] = 1.0f / (1.0f + __expf(-G_micro[t]));
    __syncthreads();

    float sGmac = 1.0f / (1.0f + __expf(-G_macro[0]));
    float T = fmaxf(fabsf(temperature[0]), 0.1f);
    float invT = 1.0f / T;

    int pi = pos_idx[i] & 7;
    float mi = m_arr[i];
    float bhi = bh_arr[i];
    float spr = spring_arr[i];
    int sloti = slot_idx[i], depi = depth[i], tpi = token_pos[i];
    bool rowskip = (coll_arr[i] != 0);

    float* srow = scores + (size_t)i * LL;
    float* arow = Amat + (size_t)i * LL;

    float x[16];
    float xmax = -3.4e38f;
#pragma unroll
    for (int c = 0; c < 16; ++c) {
        int j = t + c * 256;
        float s = 0.0f;
        if (!rowskip && j != i) {
            float mj = m_arr[j];
            float mm = mi * mj;
            int pj = pos_idx[j] & 7;
            int sd = abs(sloti - slot_idx[j]); if (sd < 1) sd = 1;
            float rs = (float)sd;
            float fmic = sigG[pi * 8 + pj] * mm * __builtin_amdgcn_rcpf(rs * rs);
            int od = abs(depi - depth[j]) + 1;
            float ro = (float)od;
            float fmac = sGmac * mm * __builtin_amdgcn_rcpf(ro * ro);
            float td = fabsf((float)(tpi - token_pos[j]));
            s = fmic + fmac + spr * td + bhi + bh_arr[j];
        }
        srow[j] = s;
        x[c] = s * invT;
        xmax = fmaxf(xmax, x[c]);
    }
    // block max
#pragma unroll
    for (int o = 32; o; o >>= 1) xmax = fmaxf(xmax, __shfl_xor(xmax, o));
    if (lane == 0) red[wid] = xmax;
    __syncthreads();
    xmax = fmaxf(fmaxf(red[0], red[1]), fmaxf(red[2], red[3]));
    __syncthreads();
    // exp + block sum
    float e[16];
    float esum = 0.0f;
#pragma unroll
    for (int c = 0; c < 16; ++c) {
        e[c] = __expf(x[c] - xmax);
        esum += e[c];
    }
#pragma unroll
    for (int o = 32; o; o >>= 1) esum += __shfl_xor(esum, o);
    if (lane == 0) red[wid] = esum;
    __syncthreads();
    float inv = 1.0f / (red[0] + red[1] + red[2] + red[3]);
#pragma unroll
    for (int c = 0; c < 16; ++c) {
        arow[t + c * 256] = e[c] * inv;
    }
}

// ---------- kernel 3: NT GEMM, bf16 MFMA ----------
// C[M][N] = A[M][K] * B[N][K]^T (+bias). 128x128 tile, 4 waves (2x2), each wave 64x64.
// LDS layout: [kb=0..3][idx=0..127][8 bf16]  (k-blocked, conflict-minimal b128 reads)
// BIAS: 0 none, 1 per-row, 2 per-col. A_BF16/B_BF16: operand dtype. OUT_BF16: C dtype.
template <int A_BF16, int B_BF16, int BIAS, int OUT_BF16>
__global__ __launch_bounds__(256) void gemm_nt_k(
    const void* __restrict__ Ap, const void* __restrict__ Bp,
    const float* __restrict__ bias, void* __restrict__ Cp,
    int M, int N, int K)
{
    __shared__ __align__(16) short lA[4096];
    __shared__ __align__(16) short lB[4096];

    int t = threadIdx.x;
    int blockN = blockIdx.x * 128, blockM = blockIdx.y * 128;
    int wid = t >> 6, lane = t & 63;
    int wm = wid >> 1, wn = wid & 1;
    int r = lane & 15, bq = lane >> 4;

    f32x4 acc[4][4];
#pragma unroll
    for (int a = 0; a < 4; ++a)
#pragma unroll
        for (int b = 0; b < 4; ++b) acc[a][b] = (f32x4){0.f, 0.f, 0.f, 0.f};

    int m0 = t >> 2;   // 0..63 (this thread's rows: m0 and m0+64)
    int kb = t & 3;    // k-block 0..3

    for (int kt = 0; kt < K; kt += 32) {
        short8 va0, va1, vb0, vb1;
        if (A_BF16) {
            const u16* A16 = (const u16*)Ap;
            va0 = *(const short8*)(A16 + (size_t)(blockM + m0) * K + kt + kb * 8);
            va1 = *(const short8*)(A16 + (size_t)(blockM + m0 + 64) * K + kt + kb * 8);
        } else {
            const float* Af = (const float*)Ap;
            const float4* p0 = (const float4*)(Af + (size_t)(blockM + m0) * K + kt + kb * 8);
            const float4* p1 = (const float4*)(Af + (size_t)(blockM + m0 + 64) * K + kt + kb * 8);
            float4 u0 = p0[0], u1 = p0[1];
            float4 u2 = p1[0], u3 = p1[1];
            va0 = pack8_bf16(u0, u1);
            va1 = pack8_bf16(u2, u3);
        }
        if (B_BF16) {
            const u16* B16 = (const u16*)Bp;
            vb0 = *(const short8*)(B16 + (size_t)(blockN + m0) * K + kt + kb * 8);
            vb1 = *(const short8*)(B16 + (size_t)(blockN + m0 + 64) * K + kt + kb * 8);
        } else {
            const float* Bf = (const float*)Bp;
            const float4* p0 = (const float4*)(Bf + (size_t)(blockN + m0) * K + kt + kb * 8);
            const float4* p1 = (const float4*)(Bf + (size_t)(blockN + m0 + 64) * K + kt + kb * 8);
            float4 u0 = p0[0], u1 = p0[1];
            float4 u2 = p1[0], u3 = p1[1];
            vb0 = pack8_bf16(u0, u1);
            vb1 = pack8_bf16(u2, u3);
        }
        __syncthreads();   // previous iter's MFMA reads done
        *(short8*)&lA[kb * 1024 + m0 * 8] = va0;
        *(short8*)&lA[kb * 1024 + (m0 + 64) * 8] = va1;
        *(short8*)&lB[kb * 1024 + m0 * 8] = vb0;
        *(short8*)&lB[kb * 1024 + (m0 + 64) * 8] = vb1;
        __syncthreads();

        short8 aF[4], bF[4];
#pragma unroll
        for (int mi = 0; mi < 4; ++mi)
            aF[mi] = *(const short8*)&lA[bq * 1024 + (wm * 64 + mi * 16 + r) * 8];
#pragma unroll
        for (int ni = 0; ni < 4; ++ni)
            bF[ni] = *(const short8*)&lB[bq * 1024 + (wn * 64 + ni * 16 + r) * 8];
#pragma unroll
        for (int mi = 0; mi < 4; ++mi)
#pragma unroll
            for (int ni = 0; ni < 4; ++ni)
                acc[mi][ni] = __builtin_amdgcn_mfma_f32_16x16x32_bf16(aF[mi], bF[ni], acc[mi][ni], 0, 0, 0);
    }

    // epilogue: C/D layout col = lane&15, row = (lane>>4)*4 + q
#pragma unroll
    for (int mi = 0; mi < 4; ++mi) {
        int rowb = blockM + wm * 64 + mi * 16 + bq * 4;
#pragma unroll
        for (int ni = 0; ni < 4; ++ni) {
            int col = blockN + wn * 64 + ni * 16 + r;
#pragma unroll
            for (int q = 0; q < 4; ++q) {
                float v = acc[mi][ni][q];
                int row = rowb + q;
                if (BIAS == 1) v += bias[row];
                else if (BIAS == 2) v += bias[col];
                if (OUT_BF16) {
                    ((u16*)Cp)[(size_t)row * N + col] = (u16)f2bf(v);
                } else {
                    ((float*)Cp)[(size_t)row * N + col] = v;
                }
            }
        }
    }
}

// ---------- launch ----------
extern "C" void kernel_launch(void* const* d_in, const int* in_sizes, int n_in,
                              void* d_out, int out_size, void* d_ws, size_t ws_size,
                              hipStream_t stream) {
    (void)in_sizes; (void)n_in; (void)out_size; (void)ws_size;
    const float* tv        = (const float*)d_in[0];
    const int* pos_idx     = (const int*)d_in[1];
    const int* depth       = (const int*)d_in[2];
    const int* token_pos   = (const int*)d_in[3];
    const int* slot_idx    = (const int*)d_in[4];
    const float* conf      = (const float*)d_in[5];
    const float* res       = (const float*)d_in[6];
    const float* G_micro   = (const float*)d_in[7];
    const float* G_macro   = (const float*)d_in[8];
    const float* k_spring  = (const float*)d_in[9];
    const float* temperature = (const float*)d_in[10];
    const float* Wv_w      = (const float*)d_in[11];
    const float* Wv_b      = (const float*)d_in[12];
    const float* Wo_w      = (const float*)d_in[13];
    const float* Wo_b      = (const float*)d_in[14];

    float* out    = (float*)d_out;                 // [L][D]
    float* Amat   = out + (size_t)LL * DD;         // [L][L]
    float* scores = Amat + (size_t)LL * LL;        // [L][L]

    // workspace: VT bf16 [D][L], H bf16 [L][D], per-token stats
    u16* VT = (u16*)d_ws;
    u16* H  = VT + (size_t)DD * LL;
    float* m_arr      = (float*)(H + (size_t)LL * DD);
    float* bh_arr     = m_arr + LL;
    float* spring_arr = bh_arr + LL;
    int*   coll_arr   = (int*)(spring_arr + LL);

    row_stats_k<<<LL, 256, 0, stream>>>(tv, pos_idx, conf, res, k_spring,
                                        m_arr, bh_arr, spring_arr, coll_arr);

    scores_k<<<LL, 256, 0, stream>>>(pos_idx, depth, token_pos, slot_idx,
                                     m_arr, bh_arr, spring_arr, coll_arr,
                                     G_micro, G_macro, temperature,
                                     scores, Amat);

    // GEMM1: VT[d][j] = sum_k Wv[d][k]*tv[j][k] + Wv_b[d]   (M=D, N=L, K=D)
    gemm_nt_k<0, 0, 1, 1><<<dim3(LL / 128, DD / 128), 256, 0, stream>>>(
        Wv_w, tv, Wv_b, VT, DD, LL, DD);

    // GEMM2: H[i][d] = sum_j A[i][j]*VT[d][j]               (M=L, N=D, K=L)
    gemm_nt_k<0, 1, 0, 1><<<dim3(DD / 128, LL / 128), 256, 0, stream>>>(
        Amat, VT, nullptr, H, LL, DD, LL);

    // GEMM3: out[i][n] = sum_d H[i][d]*Wo[n][d] + Wo_b[n]   (M=L, N=D, K=D)
    gemm_nt_k<1, 0, 2, 0><<<dim3(DD / 128, LL / 128), 256, 0, stream>>>(
        H, Wo_w, Wo_b, out, LL, DD, DD);
}

// Round 4
// 536.733 us; speedup vs baseline: 1.0173x; 1.0173x over previous
//
#include <hip/hip_runtime.h>
#include <math.h>

#define LL 4096
#define DD 2048

typedef __attribute__((ext_vector_type(8))) short short8;   // 8 x bf16
typedef __attribute__((ext_vector_type(4))) float f32x4;
typedef unsigned int u32;
typedef unsigned short u16;

__device__ __constant__ float POS_W_c[8] = {0.95f, 0.9f, 0.85f, 0.5f, 0.4f, 0.2f, 0.15f, 0.05f};

// ---------- helpers ----------
static __device__ inline u32 f2bf(float f) {
    u32 u = __builtin_bit_cast(u32, f);
    return (u + 0x7fffu + ((u >> 16) & 1u)) >> 16;
}
static __device__ inline u32 cvt2_bf16(float a, float b) {
    return f2bf(a) | (f2bf(b) << 16);
}
static __device__ inline short8 pack8_bf16(float4 a, float4 b) {
    uint4 u = make_uint4(cvt2_bf16(a.x, a.y), cvt2_bf16(a.z, a.w),
                         cvt2_bf16(b.x, b.y), cvt2_bf16(b.z, b.w));
    return __builtin_bit_cast(short8, u);
}
// async global->LDS, 16B per lane, dest = wave-uniform base + lane*16
static __device__ inline void glds16(const u16* g, u16* l) {
    __builtin_amdgcn_global_load_lds(
        (const __attribute__((address_space(1))) void*)g,
        (__attribute__((address_space(3))) void*)l, 16, 0, 0);
}

// ---------- kernel 0: fp32 -> bf16 bulk convert ----------
__global__ __launch_bounds__(256) void f32_to_bf16_k(
    const float* __restrict__ in, u16* __restrict__ out, int n8)
{
    int idx = blockIdx.x * 256 + threadIdx.x;
    int stride = gridDim.x * 256;
    for (int i = idx; i < n8; i += stride) {
        const float4* p = (const float4*)(in + (size_t)i * 8);
        float4 a = p[0], b = p[1];
        *(short8*)(out + (size_t)i * 8) = pack8_bf16(a, b);
    }
}

// ---------- kernel 1: per-token stats ----------
__global__ __launch_bounds__(256) void row_stats_k(
    const float* __restrict__ tv, const int* __restrict__ pos_idx,
    const float* __restrict__ conf, const float* __restrict__ res,
    const float* __restrict__ k_spring,
    float* __restrict__ m_arr, float* __restrict__ bh_arr,
    float* __restrict__ spring_arr, int* __restrict__ coll_arr)
{
    int i = blockIdx.x;
    int t = threadIdx.x;
    const float4* row = (const float4*)(tv + (size_t)i * DD);
    float s = 0.0f;
#pragma unroll
    for (int c = 0; c < 2; ++c) {
        float4 v = row[t + c * 256];
        s += v.x * v.x + v.y * v.y + v.z * v.z + v.w * v.w;
    }
#pragma unroll
    for (int o = 32; o; o >>= 1) s += __shfl_xor(s, o);
    __shared__ float tmp[4];
    if ((t & 63) == 0) tmp[t >> 6] = s;
    __syncthreads();
    if (t == 0) {
        float tot = tmp[0] + tmp[1] + tmp[2] + tmp[3];
        float norm = sqrtf(tot);
        int p = pos_idx[i] & 7;
        float m = norm * POS_W_c[p] * (1.0f + res[i]);
        float cf = conf[i];
        bool col = (cf <= 0.1f);
        float gap = col ? 1.0f : (cf - 0.1f);
        float bh = col ? -1e6f : (-0.01f / (gap * gap));
        m_arr[i] = m;
        bh_arr[i] = bh;
        // reference: row_skip = (bh < -1e5) — includes NEAR-collapsed rows
        coll_arr[i] = (bh < -1e5f) ? 1 : 0;
        spring_arr[i] = 1.0f / (1.0f + __expf(-k_spring[p]));
    }
}

// ---------- kernel 2: scores + row softmax (+ bf16 copy of A) ----------
__global__ __launch_bounds__(256) void scores_k(
    const int* __restrict__ pos_idx, const int* __restrict__ depth,
    const int* __restrict__ token_pos, const int* __restrict__ slot_idx,
    const float* __restrict__ m_arr, const float* __restrict__ bh_arr,
    const float* __restrict__ spring_arr, const int* __restrict__ coll_arr,
    const float* __restrict__ G_micro, const float* __restrict__ G_macro,
    const float* __restrict__ temperature,
    float* __restrict__ scores, float* __restrict__ Amat,
    u16* __restrict__ Ab)
{
    int i = blockIdx.x;
    int t = threadIdx.x;
    int lane = t & 63, wid = t >> 6;

    __shared__ float sigG[64];
    __shared__ float red[4];
    if (t < 64) sigG[t] = 1.0f / (1.0f + __expf(-G_micro[t]));
    __syncthreads();

    float sGmac = 1.0f / (1.0f + __expf(-G_macro[0]));
    float T = fmaxf(fabsf(temperature[0]), 0.1f);
    float invT = 1.0f / T;

    int pi = pos_idx[i] & 7;
    float mi = m_arr[i];
    float bhi = bh_arr[i];
    float spr = spring_arr[i];
    int sloti = slot_idx[i], depi = depth[i], tpi = token_pos[i];
    bool rowskip = (coll_arr[i] != 0);

    float* srow = scores + (size_t)i * LL;
    float* arow = Amat + (size_t)i * LL;
    u16* abrow = Ab + (size_t)i * LL;

    float x[16];
    float xmax = -3.4e38f;
#pragma unroll
    for (int c = 0; c < 16; ++c) {
        int j = t + c * 256;
        float s = 0.0f;
        if (!rowskip && j != i) {
            float mj = m_arr[j];
            float mm = mi * mj;
            int pj = pos_idx[j] & 7;
            int sd = abs(sloti - slot_idx[j]); if (sd < 1) sd = 1;
            float rs = (float)sd;
            float fmic = sigG[pi * 8 + pj] * mm * __builtin_amdgcn_rcpf(rs * rs);
            int od = abs(depi - depth[j]) + 1;
            float ro = (float)od;
            float fmac = sGmac * mm * __builtin_amdgcn_rcpf(ro * ro);
            float td = fabsf((float)(tpi - token_pos[j]));
            s = fmic + fmac + spr * td + bhi + bh_arr[j];
        }
        srow[j] = s;
        x[c] = s * invT;
        xmax = fmaxf(xmax, x[c]);
    }
#pragma unroll
    for (int o = 32; o; o >>= 1) xmax = fmaxf(xmax, __shfl_xor(xmax, o));
    if (lane == 0) red[wid] = xmax;
    __syncthreads();
    xmax = fmaxf(fmaxf(red[0], red[1]), fmaxf(red[2], red[3]));
    __syncthreads();
    float e[16];
    float esum = 0.0f;
#pragma unroll
    for (int c = 0; c < 16; ++c) {
        e[c] = __expf(x[c] - xmax);
        esum += e[c];
    }
#pragma unroll
    for (int o = 32; o; o >>= 1) esum += __shfl_xor(esum, o);
    if (lane == 0) red[wid] = esum;
    __syncthreads();
    float inv = 1.0f / (red[0] + red[1] + red[2] + red[3]);
#pragma unroll
    for (int c = 0; c < 16; ++c) {
        float a = e[c] * inv;
        arow[t + c * 256] = a;
        abrow[t + c * 256] = (u16)f2bf(a);
    }
}

// ---------- kernel 3: pure-bf16 NT GEMM (m97 structure) ----------
// C[M][N] = A[M][K] * B[N][K]^T (+bias). 128x128 tile, BK=32, 4 waves (2x2).
// LDS: fragment-ordered subtiles — subtile s (rows s*16..+15, k 0..31) stored
// as 64 lanes x 16B in lane order => global_load_lds dest is linear AND
// ds_read_b128 is contiguous per wave (conflict-free).
// BIAS: 0 none, 1 per-row, 2 per-col. OUT_BF16: C dtype.
template <int BIAS, int OUT_BF16>
__global__ __launch_bounds__(256) void gemm_bf16_k(
    const u16* __restrict__ Ap, const u16* __restrict__ Bp,
    const float* __restrict__ bias, void* __restrict__ Cp,
    int M, int N, int K)
{
    __shared__ __align__(1024) u16 lA[4096];   // 8 subtiles x 512 u16
    __shared__ __align__(1024) u16 lB[4096];

    int t = threadIdx.x;
    int wid = t >> 6, lane = t & 63;
    int wm = wid >> 1, wn = wid & 1;
    int r = lane & 15, bq = lane >> 4;
    int blockN = blockIdx.x * 128, blockM = blockIdx.y * 128;

    f32x4 acc[4][4];
#pragma unroll
    for (int a = 0; a < 4; ++a)
#pragma unroll
        for (int b = 0; b < 4; ++b) acc[a][b] = (f32x4){0.f, 0.f, 0.f, 0.f};

    // this wave stages A-subtiles {2w,2w+1} and B-subtiles {2w,2w+1}
    int s0 = wid * 2, s1 = wid * 2 + 1;
    const u16* gA0 = Ap + (size_t)(blockM + s0 * 16 + r) * K + bq * 8;
    const u16* gA1 = Ap + (size_t)(blockM + s1 * 16 + r) * K + bq * 8;
    const u16* gB0 = Bp + (size_t)(blockN + s0 * 16 + r) * K + bq * 8;
    const u16* gB1 = Bp + (size_t)(blockN + s1 * 16 + r) * K + bq * 8;

    for (int kt = 0; kt < K; kt += 32) {
        __syncthreads();                 // prev iter's LDS reads complete
        glds16(gA0 + kt, &lA[s0 * 512]);
        glds16(gA1 + kt, &lA[s1 * 512]);
        glds16(gB0 + kt, &lB[s0 * 512]);
        glds16(gB1 + kt, &lB[s1 * 512]);
        __syncthreads();                 // staging visible (vmcnt drained)

        short8 aF[4], bF[4];
#pragma unroll
        for (int mi = 0; mi < 4; ++mi)
            aF[mi] = *(const short8*)&lA[(wm * 4 + mi) * 512 + lane * 8];
#pragma unroll
        for (int ni = 0; ni < 4; ++ni)
            bF[ni] = *(const short8*)&lB[(wn * 4 + ni) * 512 + lane * 8];
#pragma unroll
        for (int mi = 0; mi < 4; ++mi)
#pragma unroll
            for (int ni = 0; ni < 4; ++ni)
                acc[mi][ni] = __builtin_amdgcn_mfma_f32_16x16x32_bf16(aF[mi], bF[ni], acc[mi][ni], 0, 0, 0);
    }

    // epilogue: C/D layout col = lane&15, row = (lane>>4)*4 + q
#pragma unroll
    for (int mi = 0; mi < 4; ++mi) {
        int rowb = blockM + wm * 64 + mi * 16 + bq * 4;
#pragma unroll
        for (int ni = 0; ni < 4; ++ni) {
            int col = blockN + wn * 64 + ni * 16 + r;
#pragma unroll
            for (int q = 0; q < 4; ++q) {
                float v = acc[mi][ni][q];
                int row = rowb + q;
                if (BIAS == 1) v += bias[row];
                else if (BIAS == 2) v += bias[col];
                if (OUT_BF16) {
                    ((u16*)Cp)[(size_t)row * N + col] = (u16)f2bf(v);
                } else {
                    ((float*)Cp)[(size_t)row * N + col] = v;
                }
            }
        }
    }
}

// ---------- launch ----------
extern "C" void kernel_launch(void* const* d_in, const int* in_sizes, int n_in,
                              void* d_out, int out_size, void* d_ws, size_t ws_size,
                              hipStream_t stream) {
    (void)in_sizes; (void)n_in; (void)out_size; (void)ws_size;
    const float* tv        = (const float*)d_in[0];
    const int* pos_idx     = (const int*)d_in[1];
    const int* depth       = (const int*)d_in[2];
    const int* token_pos   = (const int*)d_in[3];
    const int* slot_idx    = (const int*)d_in[4];
    const float* conf      = (const float*)d_in[5];
    const float* res       = (const float*)d_in[6];
    const float* G_micro   = (const float*)d_in[7];
    const float* G_macro   = (const float*)d_in[8];
    const float* k_spring  = (const float*)d_in[9];
    const float* temperature = (const float*)d_in[10];
    const float* Wv_w      = (const float*)d_in[11];
    const float* Wv_b      = (const float*)d_in[12];
    const float* Wo_w      = (const float*)d_in[13];
    const float* Wo_b      = (const float*)d_in[14];

    float* out    = (float*)d_out;                 // [L][D] fp32 (output 0)
    float* Amat   = out + (size_t)LL * DD;         // [L][L] fp32 (output 1)
    float* scores = Amat + (size_t)LL * LL;        // [L][L] fp32 (output 2)

    // Ab (bf16 A for GEMM2) lives in the `out` region: L*L*2B == L*D*4B.
    // GEMM3 overwrites it last, after GEMM2 has consumed it.
    u16* Ab = (u16*)out;

    // workspace
    u16* VT  = (u16*)d_ws;                         // [D][L] bf16
    u16* H   = VT + (size_t)DD * LL;               // [L][D] bf16
    u16* tvb = H + (size_t)LL * DD;                // [L][D] bf16
    u16* Wvb = tvb + (size_t)LL * DD;              // [D][D] bf16
    u16* Wob = Wvb + (size_t)DD * DD;              // [D][D] bf16
    float* m_arr      = (float*)(Wob + (size_t)DD * DD);
    float* bh_arr     = m_arr + LL;
    float* spring_arr = bh_arr + LL;
    int*   coll_arr   = (int*)(spring_arr + LL);

    // operand conversions (memory-bound, ~15 µs total)
    f32_to_bf16_k<<<2048, 256, 0, stream>>>(tv, tvb, LL * DD / 8);
    f32_to_bf16_k<<<1024, 256, 0, stream>>>(Wv_w, Wvb, DD * DD / 8);
    f32_to_bf16_k<<<1024, 256, 0, stream>>>(Wo_w, Wob, DD * DD / 8);

    row_stats_k<<<LL, 256, 0, stream>>>(tv, pos_idx, conf, res, k_spring,
                                        m_arr, bh_arr, spring_arr, coll_arr);

    scores_k<<<LL, 256, 0, stream>>>(pos_idx, depth, token_pos, slot_idx,
                                     m_arr, bh_arr, spring_arr, coll_arr,
                                     G_micro, G_macro, temperature,
                                     scores, Amat, Ab);

    // GEMM1: VT[d][j] = sum_k Wv[d][k]*tv[j][k] + Wv_b[d]   (M=D, N=L, K=D)
    gemm_bf16_k<1, 1><<<dim3(LL / 128, DD / 128), 256, 0, stream>>>(
        Wvb, tvb, Wv_b, VT, DD, LL, DD);

    // GEMM2: H[i][d] = sum_j A[i][j]*VT[d][j]               (M=L, N=D, K=L)
    gemm_bf16_k<0, 1><<<dim3(DD / 128, LL / 128), 256, 0, stream>>>(
        Ab, VT, nullptr, H, LL, DD, LL);

    // GEMM3: out[i][n] = sum_d H[i][d]*Wo[n][d] + Wo_b[n]   (M=L, N=D, K=D)
    gemm_bf16_k<2, 0><<<dim3(DD / 128, LL / 128), 256, 0, stream>>>(
        H, Wob, Wo_b, out, LL, DD, DD);
}

// Round 5
// 511.683 us; speedup vs baseline: 1.0672x; 1.0490x over previous
//
#include <hip/hip_runtime.h>
#include <math.h>

#define LL 4096
#define DD 2048

typedef __attribute__((ext_vector_type(8))) short short8;   // 8 x bf16
typedef __attribute__((ext_vector_type(4))) float f32x4;
typedef unsigned int u32;
typedef unsigned short u16;

__device__ __constant__ float POS_W_c[8] = {0.95f, 0.9f, 0.85f, 0.5f, 0.4f, 0.2f, 0.15f, 0.05f};

// ---------- helpers ----------
static __device__ inline u32 f2bf(float f) {
    u32 u = __builtin_bit_cast(u32, f);
    return (u + 0x7fffu + ((u >> 16) & 1u)) >> 16;
}
static __device__ inline u32 cvt2_bf16(float a, float b) {
    return f2bf(a) | (f2bf(b) << 16);
}
static __device__ inline short8 pack8_bf16(float4 a, float4 b) {
    uint4 u = make_uint4(cvt2_bf16(a.x, a.y), cvt2_bf16(a.z, a.w),
                         cvt2_bf16(b.x, b.y), cvt2_bf16(b.z, b.w));
    return __builtin_bit_cast(short8, u);
}
// async global->LDS, 16B per lane, dest = wave-uniform base + lane*16
static __device__ inline void glds16(const u16* g, u16* l) {
    __builtin_amdgcn_global_load_lds(
        (const __attribute__((address_space(1))) void*)g,
        (__attribute__((address_space(3))) void*)l, 16, 0, 0);
}

// ---------- kernel 0: fp32 -> bf16 bulk convert ----------
__global__ __launch_bounds__(256) void f32_to_bf16_k(
    const float* __restrict__ in, u16* __restrict__ out, int n8)
{
    int idx = blockIdx.x * 256 + threadIdx.x;
    int stride = gridDim.x * 256;
    for (int i = idx; i < n8; i += stride) {
        const float4* p = (const float4*)(in + (size_t)i * 8);
        float4 a = p[0], b = p[1];
        *(short8*)(out + (size_t)i * 8) = pack8_bf16(a, b);
    }
}

// ---------- kernel 1: per-token stats ----------
__global__ __launch_bounds__(256) void row_stats_k(
    const float* __restrict__ tv, const int* __restrict__ pos_idx,
    const float* __restrict__ conf, const float* __restrict__ res,
    const float* __restrict__ k_spring,
    float* __restrict__ m_arr, float* __restrict__ bh_arr,
    float* __restrict__ spring_arr, int* __restrict__ coll_arr)
{
    int i = blockIdx.x;
    int t = threadIdx.x;
    const float4* row = (const float4*)(tv + (size_t)i * DD);
    float s = 0.0f;
#pragma unroll
    for (int c = 0; c < 2; ++c) {
        float4 v = row[t + c * 256];
        s += v.x * v.x + v.y * v.y + v.z * v.z + v.w * v.w;
    }
#pragma unroll
    for (int o = 32; o; o >>= 1) s += __shfl_xor(s, o);
    __shared__ float tmp[4];
    if ((t & 63) == 0) tmp[t >> 6] = s;
    __syncthreads();
    if (t == 0) {
        float tot = tmp[0] + tmp[1] + tmp[2] + tmp[3];
        float norm = sqrtf(tot);
        int p = pos_idx[i] & 7;
        float m = norm * POS_W_c[p] * (1.0f + res[i]);
        float cf = conf[i];
        bool col = (cf <= 0.1f);
        float gap = col ? 1.0f : (cf - 0.1f);
        float bh = col ? -1e6f : (-0.01f / (gap * gap));
        m_arr[i] = m;
        bh_arr[i] = bh;
        // reference: row_skip = (bh < -1e5) — includes NEAR-collapsed rows
        coll_arr[i] = (bh < -1e5f) ? 1 : 0;
        spring_arr[i] = 1.0f / (1.0f + __expf(-k_spring[p]));
    }
}

// ---------- kernel 2: scores + row softmax (+ bf16 copy of A) ----------
__global__ __launch_bounds__(256) void scores_k(
    const int* __restrict__ pos_idx, const int* __restrict__ depth,
    const int* __restrict__ token_pos, const int* __restrict__ slot_idx,
    const float* __restrict__ m_arr, const float* __restrict__ bh_arr,
    const float* __restrict__ spring_arr, const int* __restrict__ coll_arr,
    const float* __restrict__ G_micro, const float* __restrict__ G_macro,
    const float* __restrict__ temperature,
    float* __restrict__ scores, float* __restrict__ Amat,
    u16* __restrict__ Ab)
{
    int i = blockIdx.x;
    int t = threadIdx.x;
    int lane = t & 63, wid = t >> 6;

    __shared__ float sigG[64];
    __shared__ float red[4];
    if (t < 64) sigG[t] = 1.0f / (1.0f + __expf(-G_micro[t]));
    __syncthreads();

    float sGmac = 1.0f / (1.0f + __expf(-G_macro[0]));
    float T = fmaxf(fabsf(temperature[0]), 0.1f);
    float invT = 1.0f / T;

    int pi = pos_idx[i] & 7;
    float mi = m_arr[i];
    float bhi = bh_arr[i];
    float spr = spring_arr[i];
    int sloti = slot_idx[i], depi = depth[i], tpi = token_pos[i];
    bool rowskip = (coll_arr[i] != 0);

    float* srow = scores + (size_t)i * LL;
    float* arow = Amat + (size_t)i * LL;
    u16* abrow = Ab + (size_t)i * LL;

    float x[16];
    float xmax = -3.4e38f;
#pragma unroll
    for (int c = 0; c < 16; ++c) {
        int j = t + c * 256;
        float s = 0.0f;
        if (!rowskip && j != i) {
            float mj = m_arr[j];
            float mm = mi * mj;
            int pj = pos_idx[j] & 7;
            int sd = abs(sloti - slot_idx[j]); if (sd < 1) sd = 1;
            float rs = (float)sd;
            float fmic = sigG[pi * 8 + pj] * mm * __builtin_amdgcn_rcpf(rs * rs);
            int od = abs(depi - depth[j]) + 1;
            float ro = (float)od;
            float fmac = sGmac * mm * __builtin_amdgcn_rcpf(ro * ro);
            float td = fabsf((float)(tpi - token_pos[j]));
            s = fmic + fmac + spr * td + bhi + bh_arr[j];
        }
        srow[j] = s;
        x[c] = s * invT;
        xmax = fmaxf(xmax, x[c]);
    }
#pragma unroll
    for (int o = 32; o; o >>= 1) xmax = fmaxf(xmax, __shfl_xor(xmax, o));
    if (lane == 0) red[wid] = xmax;
    __syncthreads();
    xmax = fmaxf(fmaxf(red[0], red[1]), fmaxf(red[2], red[3]));
    __syncthreads();
    float e[16];
    float esum = 0.0f;
#pragma unroll
    for (int c = 0; c < 16; ++c) {
        e[c] = __expf(x[c] - xmax);
        esum += e[c];
    }
#pragma unroll
    for (int o = 32; o; o >>= 1) esum += __shfl_xor(esum, o);
    if (lane == 0) red[wid] = esum;
    __syncthreads();
    float inv = 1.0f / (red[0] + red[1] + red[2] + red[3]);
#pragma unroll
    for (int c = 0; c < 16; ++c) {
        float a = e[c] * inv;
        arow[t + c * 256] = a;
        abrow[t + c * 256] = (u16)f2bf(a);
    }
}

// ---------- kernel 3: bf16 NT GEMM, double-buffered, counted vmcnt ----------
// C[M][N] = A[M][K]*B[N][K]^T (+bias). 128x128 tile, BK=64, 4 waves (2x2),
// LDS 2 x 32 chunks x 1KB = 64 KB. Chunk c: c<16 -> A subtile (h=c>>3,s=c&7),
// c>=16 -> B subtile. Subtile = 16 rows x 32 k, fragment-ordered (lane*16B).
// 2-phase: STAGE(next) -> vmcnt(8) -> barrier -> compute(cur) -> barrier.
// Grid: 1D 512 blocks = 8 squares (one per XCD via bid%8) of 8x8 tiles.
template <int BIAS, int OUT_BF16>
__global__ __launch_bounds__(256) void gemm_db_k(
    const u16* __restrict__ Ap, const u16* __restrict__ Bp,
    const float* __restrict__ bias, void* __restrict__ Cp,
    int M, int N, int K, int gx)
{
    __shared__ __align__(1024) u16 lds[2][32][512];   // 64 KB

    int t = threadIdx.x;
    int wid = t >> 6, lane = t & 63;
    int wm = wid >> 1, wn = wid & 1;
    int r = lane & 15, bq = lane >> 4;

    // XCD-aware 2D square swizzle: square = bid%8 (lands on one XCD),
    // 64 blocks per square cover an 8x8 tile region (8 A + 8 B panels).
    int sq = blockIdx.x & 7;
    int insq = blockIdx.x >> 3;
    int nsqx = gx >> 3;
    int sqy = sq / nsqx, sqx = sq - sqy * nsqx;
    int by = sqy * 8 + (insq >> 3);
    int bx = sqx * 8 + (insq & 7);
    int blockM = by * 128, blockN = bx * 128;

    f32x4 acc[4][4];
#pragma unroll
    for (int a = 0; a < 4; ++a)
#pragma unroll
        for (int b = 0; b < 4; ++b) acc[a][b] = (f32x4){0.f, 0.f, 0.f, 0.f};

    // this wave's 8 staging chunks
    const u16* gsrc[8];
    u16* ldst[8];
#pragma unroll
    for (int i = 0; i < 8; ++i) {
        int c = wid * 8 + i;
        int cc = c & 15;
        int h = cc >> 3, s = cc & 7;
        const u16* base = (c >> 4)
            ? Bp + (size_t)(blockN + s * 16 + r) * K
            : Ap + (size_t)(blockM + s * 16 + r) * K;
        gsrc[i] = base + h * 32 + bq * 8;
        ldst[i] = &lds[0][c][0];
    }

    int nt = K >> 6;
    // prologue: stage tile 0 into buffer 0
#pragma unroll
    for (int i = 0; i < 8; ++i) glds16(gsrc[i], ldst[i]);

    for (int tt = 0; tt < nt; ++tt) {
        int cur = tt & 1;
        if (tt + 1 < nt) {
            int kt = (tt + 1) << 6;
            int bofs = (cur ^ 1) * 16384;
#pragma unroll
            for (int i = 0; i < 8; ++i) glds16(gsrc[i] + kt, ldst[i] + bofs);
            __builtin_amdgcn_sched_barrier(0);
            asm volatile("s_waitcnt vmcnt(8)" ::: "memory");
        } else {
            __builtin_amdgcn_sched_barrier(0);
            asm volatile("s_waitcnt vmcnt(0)" ::: "memory");
        }
        __builtin_amdgcn_sched_barrier(0);
        __builtin_amdgcn_s_barrier();           // tile tt fully in lds[cur]
        __builtin_amdgcn_sched_barrier(0);

#pragma unroll
        for (int h = 0; h < 2; ++h) {
            short8 aF[4], bF[4];
#pragma unroll
            for (int mi = 0; mi < 4; ++mi)
                aF[mi] = *(const short8*)&lds[cur][h * 8 + wm * 4 + mi][lane * 8];
#pragma unroll
            for (int ni = 0; ni < 4; ++ni)
                bF[ni] = *(const short8*)&lds[cur][16 + h * 8 + wn * 4 + ni][lane * 8];
#pragma unroll
            for (int mi = 0; mi < 4; ++mi)
#pragma unroll
                for (int ni = 0; ni < 4; ++ni)
                    acc[mi][ni] = __builtin_amdgcn_mfma_f32_16x16x32_bf16(aF[mi], bF[ni], acc[mi][ni], 0, 0, 0);
        }
        __builtin_amdgcn_sched_barrier(0);
        __builtin_amdgcn_s_barrier();           // lds[cur] free for re-stage
        __builtin_amdgcn_sched_barrier(0);
    }

    // epilogue: C/D layout col = lane&15, row = (lane>>4)*4 + q
#pragma unroll
    for (int mi = 0; mi < 4; ++mi) {
        int rowb = blockM + wm * 64 + mi * 16 + bq * 4;
#pragma unroll
        for (int ni = 0; ni < 4; ++ni) {
            int col = blockN + wn * 64 + ni * 16 + r;
#pragma unroll
            for (int q = 0; q < 4; ++q) {
                float v = acc[mi][ni][q];
                int row = rowb + q;
                if (BIAS == 1) v += bias[row];
                else if (BIAS == 2) v += bias[col];
                if (OUT_BF16) {
                    ((u16*)Cp)[(size_t)row * N + col] = (u16)f2bf(v);
                } else {
                    ((float*)Cp)[(size_t)row * N + col] = v;
                }
            }
        }
    }
}

// ---------- launch ----------
extern "C" void kernel_launch(void* const* d_in, const int* in_sizes, int n_in,
                              void* d_out, int out_size, void* d_ws, size_t ws_size,
                              hipStream_t stream) {
    (void)in_sizes; (void)n_in; (void)out_size; (void)ws_size;
    const float* tv        = (const float*)d_in[0];
    const int* pos_idx     = (const int*)d_in[1];
    const int* depth       = (const int*)d_in[2];
    const int* token_pos   = (const int*)d_in[3];
    const int* slot_idx    = (const int*)d_in[4];
    const float* conf      = (const float*)d_in[5];
    const float* res       = (const float*)d_in[6];
    const float* G_micro   = (const float*)d_in[7];
    const float* G_macro   = (const float*)d_in[8];
    const float* k_spring  = (const float*)d_in[9];
    const float* temperature = (const float*)d_in[10];
    const float* Wv_w      = (const float*)d_in[11];
    const float* Wv_b      = (const float*)d_in[12];
    const float* Wo_w      = (const float*)d_in[13];
    const float* Wo_b      = (const float*)d_in[14];

    float* out    = (float*)d_out;                 // [L][D] fp32 (output 0)
    float* Amat   = out + (size_t)LL * DD;         // [L][L] fp32 (output 1)
    float* scores = Amat + (size_t)LL * LL;        // [L][L] fp32 (output 2)

    // Ab (bf16 A for GEMM2) lives in the `out` region: L*L*2B == L*D*4B.
    // GEMM3 overwrites it last, after GEMM2 has consumed it.
    u16* Ab = (u16*)out;

    // workspace
    u16* VT  = (u16*)d_ws;                         // [D][L] bf16
    u16* H   = VT + (size_t)DD * LL;               // [L][D] bf16
    u16* tvb = H + (size_t)LL * DD;                // [L][D] bf16
    u16* Wvb = tvb + (size_t)LL * DD;              // [D][D] bf16
    u16* Wob = Wvb + (size_t)DD * DD;              // [D][D] bf16
    float* m_arr      = (float*)(Wob + (size_t)DD * DD);
    float* bh_arr     = m_arr + LL;
    float* spring_arr = bh_arr + LL;
    int*   coll_arr   = (int*)(spring_arr + LL);

    // operand conversions (memory-bound)
    f32_to_bf16_k<<<2048, 256, 0, stream>>>(tv, tvb, LL * DD / 8);
    f32_to_bf16_k<<<1024, 256, 0, stream>>>(Wv_w, Wvb, DD * DD / 8);
    f32_to_bf16_k<<<1024, 256, 0, stream>>>(Wo_w, Wob, DD * DD / 8);

    row_stats_k<<<LL, 256, 0, stream>>>(tv, pos_idx, conf, res, k_spring,
                                        m_arr, bh_arr, spring_arr, coll_arr);

    scores_k<<<LL, 256, 0, stream>>>(pos_idx, depth, token_pos, slot_idx,
                                     m_arr, bh_arr, spring_arr, coll_arr,
                                     G_micro, G_macro, temperature,
                                     scores, Amat, Ab);

    // GEMM1: VT[d][j] = sum_k Wv[d][k]*tv[j][k] + Wv_b[d]   (M=D, N=L, K=D)
    gemm_db_k<1, 1><<<512, 256, 0, stream>>>(Wvb, tvb, Wv_b, VT, DD, LL, DD, LL / 128);

    // GEMM2: H[i][d] = sum_j A[i][j]*VT[d][j]               (M=L, N=D, K=L)
    gemm_db_k<0, 1><<<512, 256, 0, stream>>>(Ab, VT, nullptr, H, LL, DD, LL, DD / 128);

    // GEMM3: out[i][n] = sum_d H[i][d]*Wo[n][d] + Wo_b[n]   (M=L, N=D, K=D)
    gemm_db_k<2, 0><<<512, 256, 0, stream>>>(H, Wob, Wo_b, out, LL, DD, DD, DD / 128);
}

// Round 9
// 503.177 us; speedup vs baseline: 1.0852x; 1.0169x over previous
//
#include <hip/hip_runtime.h>
#include <math.h>

#define LL 4096
#define DD 2048

typedef __attribute__((ext_vector_type(8))) short short8;   // 8 x bf16
typedef __attribute__((ext_vector_type(4))) float f32x4;
typedef unsigned int u32;
typedef unsigned short u16;

__device__ __constant__ float POS_W_c[8] = {0.95f, 0.9f, 0.85f, 0.5f, 0.4f, 0.2f, 0.15f, 0.05f};

// ---------- helpers ----------
static __device__ inline u32 f2bf(float f) {
    u32 u = __builtin_bit_cast(u32, f);
    return (u + 0x7fffu + ((u >> 16) & 1u)) >> 16;
}
static __device__ inline u32 cvt2_bf16(float a, float b) {
    return f2bf(a) | (f2bf(b) << 16);
}
static __device__ inline short8 pack8_bf16(float4 a, float4 b) {
    uint4 u = make_uint4(cvt2_bf16(a.x, a.y), cvt2_bf16(a.z, a.w),
                         cvt2_bf16(b.x, b.y), cvt2_bf16(b.z, b.w));
    return __builtin_bit_cast(short8, u);
}
// async global->LDS, 16B per lane, dest = wave-uniform base + lane*16
static __device__ inline void glds16(const u16* g, u16* l) {
    __builtin_amdgcn_global_load_lds(
        (const __attribute__((address_space(1))) void*)g,
        (__attribute__((address_space(3))) void*)l, 16, 0, 0);
}

// ---------- kernel 0: fp32 -> bf16 bulk convert ----------
__global__ __launch_bounds__(256) void f32_to_bf16_k(
    const float* __restrict__ in, u16* __restrict__ out, int n8)
{
    int idx = blockIdx.x * 256 + threadIdx.x;
    int stride = gridDim.x * 256;
    for (int i = idx; i < n8; i += stride) {
        const float4* p = (const float4*)(in + (size_t)i * 8);
        float4 a = p[0], b = p[1];
        *(short8*)(out + (size_t)i * 8) = pack8_bf16(a, b);
    }
}

// ---------- kernel 1: per-token stats + tv bf16 conversion ----------
__global__ __launch_bounds__(256) void row_stats_k(
    const float* __restrict__ tv, const int* __restrict__ pos_idx,
    const float* __restrict__ conf, const float* __restrict__ res,
    const float* __restrict__ k_spring,
    u16* __restrict__ tvb,
    float* __restrict__ m_arr, float* __restrict__ bh_arr,
    float* __restrict__ spring_arr, int* __restrict__ coll_arr)
{
    int i = blockIdx.x;
    int t = threadIdx.x;
    const float4* row = (const float4*)(tv + (size_t)i * DD);
    float4 a = row[t * 2], b = row[t * 2 + 1];
    *(short8*)(tvb + (size_t)i * DD + t * 8) = pack8_bf16(a, b);
    float s = a.x * a.x + a.y * a.y + a.z * a.z + a.w * a.w
            + b.x * b.x + b.y * b.y + b.z * b.z + b.w * b.w;
#pragma unroll
    for (int o = 32; o; o >>= 1) s += __shfl_xor(s, o);
    __shared__ float tmp[4];
    if ((t & 63) == 0) tmp[t >> 6] = s;
    __syncthreads();
    if (t == 0) {
        float tot = tmp[0] + tmp[1] + tmp[2] + tmp[3];
        float norm = sqrtf(tot);
        int p = pos_idx[i] & 7;
        float m = norm * POS_W_c[p] * (1.0f + res[i]);
        float cf = conf[i];
        bool col = (cf <= 0.1f);
        float gap = col ? 1.0f : (cf - 0.1f);
        float bh = col ? -1e6f : (-0.01f / (gap * gap));
        m_arr[i] = m;
        bh_arr[i] = bh;
        // reference: row_skip = (bh < -1e5) — includes NEAR-collapsed rows
        coll_arr[i] = (bh < -1e5f) ? 1 : 0;
        spring_arr[i] = 1.0f / (1.0f + __expf(-k_spring[p]));
    }
}

// ---------- kernel 2: scores + row softmax (+ bf16 copy of A) ----------
__global__ __launch_bounds__(256) void scores_k(
    const int* __restrict__ pos_idx, const int* __restrict__ depth,
    const int* __restrict__ token_pos, const int* __restrict__ slot_idx,
    const float* __restrict__ m_arr, const float* __restrict__ bh_arr,
    const float* __restrict__ spring_arr, const int* __restrict__ coll_arr,
    const float* __restrict__ G_micro, const float* __restrict__ G_macro,
    const float* __restrict__ temperature,
    float* __restrict__ scores, float* __restrict__ Amat,
    u16* __restrict__ Ab)
{
    int i = blockIdx.x;
    int t = threadIdx.x;
    int lane = t & 63, wid = t >> 6;

    __shared__ float sigG[64];
    __shared__ float red[4];
    if (t < 64) sigG[t] = 1.0f / (1.0f + __expf(-G_micro[t]));
    __syncthreads();

    float sGmac = 1.0f / (1.0f + __expf(-G_macro[0]));
    float T = fmaxf(fabsf(temperature[0]), 0.1f);
    float invT = 1.0f / T;

    int pi = pos_idx[i] & 7;
    float mi = m_arr[i];
    float bhi = bh_arr[i];
    float spr = spring_arr[i];
    int sloti = slot_idx[i], depi = depth[i], tpi = token_pos[i];
    bool rowskip = (coll_arr[i] != 0);

    float* srow = scores + (size_t)i * LL;
    float* arow = Amat + (size_t)i * LL;
    u16* abrow = Ab + (size_t)i * LL;

    float x[16];
    float xmax = -3.4e38f;
#pragma unroll
    for (int c = 0; c < 16; ++c) {
        int j = t + c * 256;
        float s = 0.0f;
        if (!rowskip && j != i) {
            float mj = m_arr[j];
            float mm = mi * mj;
            int pj = pos_idx[j] & 7;
            int sd = abs(sloti - slot_idx[j]); if (sd < 1) sd = 1;
            float rs = (float)sd;
            float fmic = sigG[pi * 8 + pj] * mm * __builtin_amdgcn_rcpf(rs * rs);
            int od = abs(depi - depth[j]) + 1;
            float ro = (float)od;
            float fmac = sGmac * mm * __builtin_amdgcn_rcpf(ro * ro);
            float td = fabsf((float)(tpi - token_pos[j]));
            s = fmic + fmac + spr * td + bhi + bh_arr[j];
        }
        srow[j] = s;
        x[c] = s * invT;
        xmax = fmaxf(xmax, x[c]);
    }
#pragma unroll
    for (int o = 32; o; o >>= 1) xmax = fmaxf(xmax, __shfl_xor(xmax, o));
    if (lane == 0) red[wid] = xmax;
    __syncthreads();
    xmax = fmaxf(fmaxf(red[0], red[1]), fmaxf(red[2], red[3]));
    __syncthreads();
    float e[16];
    float esum = 0.0f;
#pragma unroll
    for (int c = 0; c < 16; ++c) {
        e[c] = __expf(x[c] - xmax);
        esum += e[c];
    }
#pragma unroll
    for (int o = 32; o; o >>= 1) esum += __shfl_xor(esum, o);
    if (lane == 0) red[wid] = esum;
    __syncthreads();
    float inv = 1.0f / (red[0] + red[1] + red[2] + red[3]);
#pragma unroll
    for (int c = 0; c < 16; ++c) {
        float a = e[c] * inv;
        arow[t + c * 256] = a;
        abrow[t + c * 256] = (u16)f2bf(a);
    }
}

// ---------- kernel 3: bf16 NT GEMM, depth-4 circular pipeline ----------
// C[M][N] = A[M][K]*B[N][K]^T (+bias). 128x128 tile, BK=32, 4 waves (2x2).
// LDS: 4 buffers x 16 chunks x 1KB = 64 KB. Chunk c<8: A subtile c (16 rows
// x 32 k, fragment-ordered lane*16B); c>=8: B subtile c-8.
// Pipeline: at iter t wait vmcnt(8) (= tile t's 4 loads done, tiles t+1/t+2
// in flight), ONE barrier, then issue tile t+3 into buf[(t+3)&3] (whose reads
// finished at iter t-1), then compute tile t. Loads get ~3 compute phases.
// Grid: 1D 512 blocks = 8 squares (one per XCD via bid%8) of 8x8 tiles.
template <int BIAS, int OUT_BF16>
__global__ __launch_bounds__(256) void gemm_p4_k(
    const u16* __restrict__ Ap, const u16* __restrict__ Bp,
    const float* __restrict__ bias, void* __restrict__ Cp,
    int M, int N, int K, int gx)
{
    __shared__ __align__(1024) u16 ldsF[4 * 16 * 512];   // 64 KB

    int t = threadIdx.x;
    int wid = t >> 6, lane = t & 63;
    int wm = wid >> 1, wn = wid & 1;
    int r = lane & 15, bq = lane >> 4;

    // XCD-aware 2D square swizzle: square = bid%8 (lands on one XCD),
    // 64 blocks per square cover an 8x8 tile region (8 A + 8 B panels).
    int sq = blockIdx.x & 7;
    int insq = blockIdx.x >> 3;
    int nsqx = gx >> 3;
    int sqy = sq / nsqx, sqx = sq - sqy * nsqx;
    int by = sqy * 8 + (insq >> 3);
    int bx = sqx * 8 + (insq & 7);
    int blockM = by * 128, blockN = bx * 128;

    f32x4 acc[4][4];
#pragma unroll
    for (int a = 0; a < 4; ++a)
#pragma unroll
        for (int b = 0; b < 4; ++b) acc[a][b] = (f32x4){0.f, 0.f, 0.f, 0.f};

    // this wave's 4 staging chunks (w0:A0-3, w1:A4-7, w2:B0-3, w3:B4-7)
    const u16* gsrc[4];
    u16* ldst[4];
#pragma unroll
    for (int i = 0; i < 4; ++i) {
        int c = wid * 4 + i;
        int s = c & 7;
        const u16* base = (c >> 3)
            ? Bp + (size_t)(blockN + s * 16 + r) * K
            : Ap + (size_t)(blockM + s * 16 + r) * K;
        gsrc[i] = base + bq * 8;
        ldst[i] = &ldsF[c * 512];
    }

    int nt = K >> 5;   // >= 64 for all our shapes
    // prologue: stage tiles 0,1,2 into buffers 0,1,2
#pragma unroll
    for (int i = 0; i < 4; ++i) glds16(gsrc[i], ldst[i]);
#pragma unroll
    for (int i = 0; i < 4; ++i) glds16(gsrc[i] + 32, ldst[i] + 8192);
#pragma unroll
    for (int i = 0; i < 4; ++i) glds16(gsrc[i] + 64, ldst[i] + 16384);

    for (int tt = 0; tt < nt; ++tt) {
        // wait: my 4 loads for tile tt are done (t+1,t+2 remain in flight)
        if (tt + 2 < nt)      asm volatile("s_waitcnt vmcnt(8)" ::: "memory");
        else if (tt + 1 < nt) asm volatile("s_waitcnt vmcnt(4)" ::: "memory");
        else                  asm volatile("s_waitcnt vmcnt(0)" ::: "memory");
        __builtin_amdgcn_sched_barrier(0);
        __builtin_amdgcn_s_barrier();   // all waves' tile-tt data landed;
        __builtin_amdgcn_sched_barrier(0);  // all reads of tile tt-1 done

        if (tt + 3 < nt) {
            int kt = (tt + 3) << 5;
            int bofs = ((tt + 3) & 3) * 8192;
#pragma unroll
            for (int i = 0; i < 4; ++i) glds16(gsrc[i] + kt, ldst[i] + bofs);
        }

        int cb = (tt & 3) * 8192;
        short8 aF[4], bF[4];
#pragma unroll
        for (int mi = 0; mi < 4; ++mi)
            aF[mi] = *(const short8*)&ldsF[cb + (wm * 4 + mi) * 512 + lane * 8];
#pragma unroll
        for (int ni = 0; ni < 4; ++ni)
            bF[ni] = *(const short8*)&ldsF[cb + (8 + wn * 4 + ni) * 512 + lane * 8];
#pragma unroll
        for (int mi = 0; mi < 4; ++mi)
#pragma unroll
            for (int ni = 0; ni < 4; ++ni)
                acc[mi][ni] = __builtin_amdgcn_mfma_f32_16x16x32_bf16(aF[mi], bF[ni], acc[mi][ni], 0, 0, 0);
    }

    // epilogue: C/D layout col = lane&15, row = (lane>>4)*4 + q
#pragma unroll
    for (int mi = 0; mi < 4; ++mi) {
        int rowb = blockM + wm * 64 + mi * 16 + bq * 4;
#pragma unroll
        for (int ni = 0; ni < 4; ++ni) {
            int col = blockN + wn * 64 + ni * 16 + r;
#pragma unroll
            for (int q = 0; q < 4; ++q) {
                float v = acc[mi][ni][q];
                int row = rowb + q;
                if (BIAS == 1) v += bias[row];
                else if (BIAS == 2) v += bias[col];
                if (OUT_BF16) {
                    ((u16*)Cp)[(size_t)row * N + col] = (u16)f2bf(v);
                } else {
                    ((float*)Cp)[(size_t)row * N + col] = v;
                }
            }
        }
    }
}

// ---------- launch ----------
extern "C" void kernel_launch(void* const* d_in, const int* in_sizes, int n_in,
                              void* d_out, int out_size, void* d_ws, size_t ws_size,
                              hipStream_t stream) {
    (void)in_sizes; (void)n_in; (void)out_size; (void)ws_size;
    const float* tv        = (const float*)d_in[0];
    const int* pos_idx     = (const int*)d_in[1];
    const int* depth       = (const int*)d_in[2];
    const int* token_pos   = (const int*)d_in[3];
    const int* slot_idx    = (const int*)d_in[4];
    const float* conf      = (const float*)d_in[5];
    const float* res       = (const float*)d_in[6];
    const float* G_micro   = (const float*)d_in[7];
    const float* G_macro   = (const float*)d_in[8];
    const float* k_spring  = (const float*)d_in[9];
    const float* temperature = (const float*)d_in[10];
    const float* Wv_w      = (const float*)d_in[11];
    const float* Wv_b      = (const float*)d_in[12];
    const float* Wo_w      = (const float*)d_in[13];
    const float* Wo_b      = (const float*)d_in[14];

    float* out    = (float*)d_out;                 // [L][D] fp32 (output 0)
    float* Amat   = out + (size_t)LL * DD;         // [L][L] fp32 (output 1)
    float* scores = Amat + (size_t)LL * LL;        // [L][L] fp32 (output 2)

    // Ab (bf16 A for GEMM2) lives in the `out` region: L*L*2B == L*D*4B.
    // GEMM3 overwrites it last, after GEMM2 has consumed it.
    u16* Ab = (u16*)out;

    // workspace
    u16* VT  = (u16*)d_ws;                         // [D][L] bf16
    u16* H   = VT + (size_t)DD * LL;               // [L][D] bf16
    u16* tvb = H + (size_t)LL * DD;                // [L][D] bf16
    u16* Wvb = tvb + (size_t)LL * DD;              // [D][D] bf16
    u16* Wob = Wvb + (size_t)DD * DD;              // [D][D] bf16
    float* m_arr      = (float*)(Wob + (size_t)DD * DD);
    float* bh_arr     = m_arr + LL;
    float* spring_arr = bh_arr + LL;
    int*   coll_arr   = (int*)(spring_arr + LL);

    // weight conversions (memory-bound); tv converted inside row_stats_k
    f32_to_bf16_k<<<1024, 256, 0, stream>>>(Wv_w, Wvb, DD * DD / 8);
    f32_to_bf16_k<<<1024, 256, 0, stream>>>(Wo_w, Wob, DD * DD / 8);

    row_stats_k<<<LL, 256, 0, stream>>>(tv, pos_idx, conf, res, k_spring,
                                        tvb, m_arr, bh_arr, spring_arr, coll_arr);

    scores_k<<<LL, 256, 0, stream>>>(pos_idx, depth, token_pos, slot_idx,
                                     m_arr, bh_arr, spring_arr, coll_arr,
                                     G_micro, G_macro, temperature,
                                     scores, Amat, Ab);

    // GEMM1: VT[d][j] = sum_k Wv[d][k]*tv[j][k] + Wv_b[d]   (M=D, N=L, K=D)
    gemm_p4_k<1, 1><<<512, 256, 0, stream>>>(Wvb, tvb, Wv_b, VT, DD, LL, DD, LL / 128);

    // GEMM2: H[i][d] = sum_j A[i][j]*VT[d][j]               (M=L, N=D, K=L)
    gemm_p4_k<0, 1><<<512, 256, 0, stream>>>(Ab, VT, nullptr, H, LL, DD, LL, DD / 128);

    // GEMM3: out[i][n] = sum_d H[i][d]*Wo[n][d] + Wo_b[n]   (M=L, N=D, K=D)
    gemm_p4_k<2, 0><<<512, 256, 0, stream>>>(H, Wob, Wo_b, out, LL, DD, DD, DD / 128);
}